// Round 1
// baseline (395.610 us; speedup 1.0000x reference)
//
#include <hip/hip_runtime.h>
#include <stdint.h>

#define T_ 128
#define HASH_MASK 0xFFFFu

typedef unsigned short us2 __attribute__((ext_vector_type(2)));

static __device__ __forceinline__ unsigned pkadd(unsigned a, unsigned b) {
  us2 x = __builtin_bit_cast(us2, a);
  us2 y = __builtin_bit_cast(us2, b);
  us2 r = x + y;                      // v_pk_add_u16: u16 wrap == mod 65536
  return __builtin_bit_cast(unsigned, r);
}

// Build packed pair-coefficient table cpack[40][1024].
// Thread role in scan: tid = 4*j + q. Pairs p<32 are state terms
// (cols 64 + 64q + 2p, +1); p in [32,40) are window terms (cols 2*(8q+(p-32)), +1).
__global__ void prep_kernel(const int* __restrict__ sc, unsigned* __restrict__ cpack) {
  int idx = blockIdx.x * 256 + threadIdx.x;
  if (idx >= 40 * 1024) return;
  int p = idx >> 10, tid = idx & 1023;
  int j = tid >> 2, q = tid & 3;
  int col;
  if (p < 32) col = 64 + 64 * q + 2 * p;
  else        col = 2 * (8 * q + (p - 32));
  unsigned lo = (unsigned)sc[j * 320 + col] & 0xFFFFu;
  unsigned hi = (unsigned)sc[j * 320 + col + 1] & 0xFFFFu;
  cpack[idx] = lo | (hi << 16);
}

// One block per batch row b; 1024 threads = 4 partial-dot threads per state j.
// Per step: phase A = masked packed dot from registers, phase B = reduce +
// gather + threshold + ballot -> next-step masks.
__global__ __launch_bounds__(1024) void scan_kernel(
    const unsigned* __restrict__ cpack,
    const int2* __restrict__ bits2,
    const float* __restrict__ state_mem,
    unsigned* __restrict__ fs) {
  // mask rows padded to 44 words: words 0..31 = state pair masks,
  // 32..39 = window pair masks, 40..43 pad (bank-decorrelates the 4 q rows).
  __shared__ __align__(16) unsigned maskw[4][44];
  __shared__ __align__(16) unsigned partials[1024];
  const int tid = threadIdx.x;
  const int b = blockIdx.x;
  const int q = tid & 3;

  unsigned c[40];
#pragma unroll
  for (int p = 0; p < 40; ++p) c[p] = cpack[p * 1024 + tid];

  // state0 = 0 -> state masks zero; build window masks for t=0
  unsigned* mflat = &maskw[0][0];
  if (tid < 176) {
    int col = tid % 44;
    if (col < 32 || col >= 40) mflat[tid] = 0u;
  }
  if (tid < 32) {
    int2 v = bits2[b * 4096 + tid];
    maskw[tid >> 3][32 + (tid & 7)] =
        (v.x ? 0xFFFFu : 0u) | (v.y ? 0xFFFF0000u : 0u);
  }
  __syncthreads();

  const uint4* row4 = (const uint4*)(&maskw[q][0]);

  for (int t = 0; t < T_; ++t) {
    // ---- phase A: packed masked dot over register-resident coefficients
    unsigned acc = 0;
#pragma unroll
    for (int c4 = 0; c4 < 10; ++c4) {
      uint4 m = row4[c4];
      acc = pkadd(acc, c[4 * c4 + 0] & m.x);
      acc = pkadd(acc, c[4 * c4 + 1] & m.y);
      acc = pkadd(acc, c[4 * c4 + 2] & m.z);
      acc = pkadd(acc, c[4 * c4 + 3] & m.w);
    }
    partials[tid] = (acc & 0xFFFFu) + (acc >> 16);
    __syncthreads();

    // ---- phase B
    if (tid < 256) {
      uint4 p4 = ((const uint4*)partials)[tid];
      unsigned addr = (p4.x + p4.y + p4.z + p4.w) & HASH_MASK;
      float v = state_mem[((size_t)tid << 16) + addr];
      unsigned long long m = __ballot(v >= 0.5f);
      int l = tid & 63, w = tid >> 6;
      if (l < 32) {
        unsigned two = (unsigned)(m >> (2 * l)) & 3u;
        maskw[w][l] = ((two & 1u) ? 0xFFFFu : 0u) | ((two & 2u) ? 0xFFFF0000u : 0u);
      }
      if (t == T_ - 1 && l == 0) {
        fs[b * 8 + 2 * w]     = (unsigned)m;
        fs[b * 8 + 2 * w + 1] = (unsigned)(m >> 32);
      }
    } else if (tid < 288 && t + 1 < T_) {
      // idle wave builds window masks for step t+1 (hides the global load)
      int l = tid - 256;
      int2 v = bits2[b * 4096 + (t + 1) * 32 + l];
      maskw[l >> 3][32 + (l & 7)] =
          (v.x ? 0xFFFFu : 0u) | (v.y ? 0xFFFF0000u : 0u);
    }
    __syncthreads();
  }
}

// Only the selected head per batch row is evaluated.
__global__ void heads_kernel(const int* __restrict__ bits,
                             const unsigned* __restrict__ fs,
                             const int* __restrict__ head_conn,
                             const int* __restrict__ head_coeffs,
                             const float* __restrict__ head_mem,
                             float* __restrict__ out) {
  __shared__ unsigned fsw[8];
  int b = blockIdx.x, o = threadIdx.x;
  if (o < 8) fsw[o] = fs[b * 8 + o];
  __syncthreads();
  const int* wrow = bits + b * 8192 + 127 * 64;
  int h = ((wrow[61] << 2) + (wrow[62] << 1) + wrow[63]) & 7;
  int ho = h * 64 + o;
  int base = ho * 8;
  unsigned addr = 0;
#pragma unroll
  for (int k = 0; k < 8; ++k) {
    int cn = head_conn[base + k];
    unsigned bit = (fsw[cn >> 5] >> (cn & 31)) & 1u;
    addr += bit * (unsigned)head_coeffs[base + k];
  }
  addr &= HASH_MASK;
  out[b * 64 + o] = head_mem[((size_t)ho << 16) + addr];
}

extern "C" void kernel_launch(void* const* d_in, const int* in_sizes, int n_in,
                              void* d_out, int out_size, void* d_ws, size_t ws_size,
                              hipStream_t stream) {
  const int*   bits         = (const int*)d_in[0];
  const int*   state_coeffs = (const int*)d_in[1];
  const float* state_mem    = (const float*)d_in[2];
  const int*   head_conn    = (const int*)d_in[3];
  const int*   head_coeffs  = (const int*)d_in[4];
  const float* head_mem     = (const float*)d_in[5];
  float* out = (float*)d_out;

  unsigned* cpack = (unsigned*)d_ws;                        // 40*1024*4 = 160 KiB
  unsigned* fs    = (unsigned*)((char*)d_ws + 40 * 1024 * 4); // 128*8*4 = 4 KiB

  prep_kernel<<<160, 256, 0, stream>>>(state_coeffs, cpack);
  scan_kernel<<<128, 1024, 0, stream>>>(cpack, (const int2*)bits, state_mem, fs);
  heads_kernel<<<128, 64, 0, stream>>>(bits, fs, head_conn, head_coeffs,
                                       head_mem, out);
}

// Round 2
// 381.174 us; speedup vs baseline: 1.0379x; 1.0379x over previous
//
#include <hip/hip_runtime.h>
#include <stdint.h>

#define T_ 128

typedef unsigned short us2 __attribute__((ext_vector_type(2)));
typedef unsigned uint8v __attribute__((ext_vector_type(8)));

#if defined(__has_builtin)
#if __has_builtin(__builtin_amdgcn_udot2)
#define HAVE_UDOT2 1
#endif
#endif

// acc += a.lo*b.lo + a.hi*b.hi  (u16 lanes, u32 accumulate)
static __device__ __forceinline__ unsigned dot2(unsigned a, unsigned b, unsigned acc) {
#ifdef HAVE_UDOT2
  return __builtin_amdgcn_udot2(__builtin_bit_cast(us2, a),
                                __builtin_bit_cast(us2, b), acc, false);
#else
  return acc + (a & 0xFFFFu) * (b & 0xFFFFu) + (a >> 16) * (b >> 16);
#endif
}

// ---------------------------------------------------------------------------
// prep 1: packed pair coefficients cpack[p][tid], p<32 state pairs, 32..39 window.
// Thread tid in scan: wave w=tid>>6, lane l=tid&63; q=w>>2, r=w&3, j=64r+l.
// state pair p: cols 64+64q+2p (+1) == state bits 64q+2p (ballot bits 2p,2p+1)
// window pair i: cols 2*(8q+i) (+1)
__global__ void prep_coeff(const int* __restrict__ sc, unsigned* __restrict__ cpack) {
  int idx = blockIdx.x * 256 + threadIdx.x;
  if (idx >= 40 * 1024) return;
  int p = idx >> 10, tid = idx & 1023;
  int w = tid >> 6, l = tid & 63;
  int q = w >> 2, r = w & 3;
  int j = (r << 6) + l;
  int col;
  if (p < 32) col = 64 + 64 * q + 2 * p;
  else        col = 2 * (8 * q + (p - 32));
  unsigned lo = (unsigned)sc[j * 320 + col] & 0xFFFFu;
  unsigned hi = (unsigned)sc[j * 320 + col + 1] & 0xFFFFu;
  cpack[idx] = lo | (hi << 16);
}

// prep 2: window pair operands wpair[b][t][q][i] = w[2*(8q+i)] | w[2*(8q+i)+1]<<16
__global__ void prep_wpair(const int* __restrict__ bits, unsigned* __restrict__ wpair) {
  int idx = blockIdx.x * 256 + threadIdx.x;
  if (idx >= 128 * 128 * 32) return;
  int i = idx & 7, q = (idx >> 3) & 3, t = (idx >> 5) & 127, b = idx >> 12;
  int col = 2 * (8 * q + i);
  unsigned lo = (unsigned)bits[b * 8192 + t * 64 + col];
  unsigned hi = (unsigned)bits[b * 8192 + t * 64 + col + 1];
  wpair[idx] = lo | (hi << 16);
}

// prep 3: bitpack (state_mem >= 0.5) into packed[j][2048] u32 (2 MiB total)
__global__ void prep_bitpack(const float* __restrict__ sm, unsigned long long* __restrict__ packed) {
  int gid = blockIdx.x * 256 + threadIdx.x;
  int wave = gid >> 6, lane = gid & 63;
  int j = wave >> 10, wg = wave & 1023;
  float v = sm[((size_t)j << 16) + (wg << 6) + lane];
  unsigned long long m = __ballot(v >= 0.5f);
  if (lane == 0) packed[(j << 10) + wg] = m;
}

// ---------------------------------------------------------------------------
// scan: 1 block per batch row, 16 waves. Wave w: q=w>>2, r=w&3.
// Phase A: per-thread dot of 80 cols (40 u16 pairs) with wave-uniform bit
// operands expanded on the scalar pipe from this wave's own ballot.
// Phase B: wave gathers state bits for j2=64q+lane from the 2 MiB packed
// table (L2-resident), ballots into SGPRs for the next step.
__global__ __launch_bounds__(1024) void scan_kernel(
    const unsigned* __restrict__ cpack,
    const unsigned* __restrict__ wpair,
    const unsigned* __restrict__ packed32,
    unsigned* __restrict__ fs) {
  __shared__ unsigned part[2][1024];
  const int tid = threadIdx.x;
  const int b = blockIdx.x;
  const int w = tid >> 6, l = tid & 63;
  const int q = __builtin_amdgcn_readfirstlane(w >> 2);  // wave-uniform for s_load
  const int r = w & 3;
  const int j = (r << 6) + l;   // row this thread's partial dot serves
  const int j2 = (q << 6) + l;  // row this wave gathers / ballots

  unsigned c[40];
#pragma unroll
  for (int p = 0; p < 40; ++p) c[p] = cpack[(p << 10) + tid];

  const uint8v* wq = (const uint8v*)(wpair + (b << 12) + (q << 3));
  // step stride in uint8v units: 32 words / 8 = 4
  uint8v wcur = wq[0];

  unsigned long long m = 0ULL;  // state bits [64q,64q+64), state0 = 0

#pragma unroll 1
  for (int t = 0; t < T_; ++t) {
    // prefetch next step's window operands (uniform 32B load)
    int tn = (t + 1 < T_) ? (t + 1) : t;
    uint8v wnext = wq[tn << 2];

    // ---- phase A: 40 dot2, bit operands built on the scalar pipe
    unsigned a0 = 0, a1 = 0, a2 = 0, a3 = 0;
#pragma unroll
    for (int k = 0; k < 8; ++k) {
      unsigned byte = (unsigned)(m >> (8 * k)) & 0xFFu;
      unsigned t0 = byte;
      unsigned t1 = byte >> 2;
      unsigned t2 = byte >> 4;
      unsigned t3 = byte >> 6;
      a0 = dot2((t0 | (t0 << 15)) & 0x10001u, c[4 * k + 0], a0);
      a1 = dot2((t1 | (t1 << 15)) & 0x10001u, c[4 * k + 1], a1);
      a2 = dot2((t2 | (t2 << 15)) & 0x10001u, c[4 * k + 2], a2);
      a3 = dot2((t3 | (t3 << 15)) & 0x10001u, c[4 * k + 3], a3);
    }
#pragma unroll
    for (int i = 0; i < 8; i += 4) {
      a0 = dot2(wcur[i + 0], c[32 + i + 0], a0);
      a1 = dot2(wcur[i + 1], c[32 + i + 1], a1);
      a2 = dot2(wcur[i + 2], c[32 + i + 2], a2);
      a3 = dot2(wcur[i + 3], c[32 + i + 3], a3);
    }
    part[t & 1][(j << 2) + q] = a0 + a1 + a2 + a3;
    __syncthreads();

    // ---- phase B: reduce 4 partials, gather packed state bit, ballot
    uint4 p4 = ((const uint4*)part[t & 1])[j2];
    unsigned addr = (p4.x + p4.y + p4.z + p4.w) & 0xFFFFu;
    unsigned word = packed32[((size_t)j2 << 11) + (addr >> 5)];
    m = __ballot(((word >> (addr & 31)) & 1u) != 0u);

    wcur = wnext;
  }

  if (r == 0 && l == 0) {
    fs[(b << 3) + (q << 1)] = (unsigned)m;
    fs[(b << 3) + (q << 1) + 1] = (unsigned)(m >> 32);
  }
}

// ---------------------------------------------------------------------------
// heads: only the selected head per batch row
__global__ void heads_kernel(const int* __restrict__ bits,
                             const unsigned* __restrict__ fs,
                             const int* __restrict__ head_conn,
                             const int* __restrict__ head_coeffs,
                             const float* __restrict__ head_mem,
                             float* __restrict__ out) {
  __shared__ unsigned fsw[8];
  int b = blockIdx.x, o = threadIdx.x;
  if (o < 8) fsw[o] = fs[b * 8 + o];
  __syncthreads();
  const int* wrow = bits + b * 8192 + 127 * 64;
  int h = ((wrow[61] << 2) + (wrow[62] << 1) + wrow[63]) & 7;
  int ho = h * 64 + o;
  int base = ho * 8;
  unsigned addr = 0;
#pragma unroll
  for (int k = 0; k < 8; ++k) {
    int cn = head_conn[base + k];
    unsigned bit = (fsw[cn >> 5] >> (cn & 31)) & 1u;
    addr += bit * (unsigned)head_coeffs[base + k];
  }
  addr &= 0xFFFFu;
  out[b * 64 + o] = head_mem[((size_t)ho << 16) + addr];
}

extern "C" void kernel_launch(void* const* d_in, const int* in_sizes, int n_in,
                              void* d_out, int out_size, void* d_ws, size_t ws_size,
                              hipStream_t stream) {
  const int*   bits         = (const int*)d_in[0];
  const int*   state_coeffs = (const int*)d_in[1];
  const float* state_mem    = (const float*)d_in[2];
  const int*   head_conn    = (const int*)d_in[3];
  const int*   head_coeffs  = (const int*)d_in[4];
  const float* head_mem     = (const float*)d_in[5];
  float* out = (float*)d_out;

  char* ws = (char*)d_ws;
  unsigned* cpack  = (unsigned*)ws;                       // 40*1024*4   = 160 KiB
  unsigned* wpair  = (unsigned*)(ws + (160 << 10));       // 128*128*32*4 = 2 MiB
  unsigned* packed = (unsigned*)(ws + (160 << 10) + (2 << 20)); // 2 MiB
  unsigned* fs     = (unsigned*)(ws + (160 << 10) + (4 << 20)); // 4 KiB

  prep_coeff<<<160, 256, 0, stream>>>(state_coeffs, cpack);
  prep_wpair<<<2048, 256, 0, stream>>>(bits, wpair);
  prep_bitpack<<<65536, 256, 0, stream>>>(state_mem, (unsigned long long*)packed);
  scan_kernel<<<128, 1024, 0, stream>>>(cpack, wpair, packed, fs);
  heads_kernel<<<128, 64, 0, stream>>>(bits, fs, head_conn, head_coeffs,
                                       head_mem, out);
}

// Round 3
// 348.944 us; speedup vs baseline: 1.1337x; 1.0924x over previous
//
#include <hip/hip_runtime.h>
#include <stdint.h>

#define T_ 128

typedef int v4i __attribute__((ext_vector_type(4)));

// ---------------------------------------------------------------------------
// prep 1: static B-fragments for mfma_i32_16x16x64_i8, biased i8 (byte-128).
// Fragment mf = (tau*5 + kappa)*2 + h  (tau: N-tile of 16 j's, kappa: K-chunk
// of 64 cols, h: 0=lo byte, 1=hi byte). Lane l holds n = l&15,
// k-slots kin = (l>>4)*16 + 4r + b  (reg r, byte b) — the SAME slot->k map the
// scan uses for A, so any HW k-permutation cancels in the dot.
__global__ void prep_bfrag(const int* __restrict__ sc, uint4* __restrict__ bf) {
  int gid = blockIdx.x * 256 + threadIdx.x;
  if (gid >= 160 * 64) return;
  int mf = gid >> 6, l = gid & 63;
  int tau = mf / 10, rem = mf % 10;
  int kap = rem >> 1, h = rem & 1;
  int j = 16 * tau + (l & 15);
  int kinb = (l >> 4) * 16;
  unsigned wout[4];
#pragma unroll
  for (int r = 0; r < 4; ++r) {
    unsigned wrd = 0;
#pragma unroll
    for (int be = 0; be < 4; ++be) {
      int kin = kinb + 4 * r + be;
      int col = (kap == 0) ? kin : 64 + ((kap - 1) << 6) + kin;
      unsigned c = (unsigned)sc[j * 320 + col];
      unsigned byte = (h ? (c >> 8) : c) & 0xFFu;
      byte = (byte - 128u) & 0xFFu;  // bias so values fit signed i8
      wrd |= byte << (8 * be);
    }
    wout[r] = wrd;
  }
  bf[gid] = make_uint4(wout[0], wout[1], wout[2], wout[3]);
}

// prep 2: window bits packed to u64 per (b,t)
__global__ void prep_wbits(const int* __restrict__ bits,
                           unsigned long long* __restrict__ wb) {
  int gid = blockIdx.x * 256 + threadIdx.x;  // 4096 blocks * 256 = 1M
  int wv = gid >> 6, lane = gid & 63;
  unsigned long long m = __ballot(bits[gid] != 0);
  if (lane == 0) wb[wv] = m;
}

// prep 3: bitpack (state_mem >= 0.5) -> 2 MiB table (L2-resident for scan)
__global__ void prep_bitpack(const float* __restrict__ sm,
                             unsigned long long* __restrict__ packed) {
  int base = blockIdx.x * (256 * 32) + threadIdx.x;  // 2048 blocks
  int lane = threadIdx.x & 63;
#pragma unroll 1
  for (int it = 0; it < 32; ++it) {
    int idx = base + it * 256;
    float v = sm[idx];
    unsigned long long m = __ballot(v >= 0.5f);
    if (lane == 0) packed[idx >> 6] = m;
  }
}

// ---------------------------------------------------------------------------
// scan + heads: 1 block per batch row, 8 waves. Wave w owns N-tiles {2w,2w+1}.
// Per step: A-frag built per-lane from 5 uniform 64-bit chunks (window + 4
// state ballots), 20 i8 MFMAs, addr epilogue -> LDS, waves 0-3 gather packed
// state bits + ballot -> LDS, all waves pick up new state. Heads fused.
__global__ __launch_bounds__(512) void scan_heads(
    const uint4* __restrict__ bfrag,
    const unsigned long long* __restrict__ wbits,
    const unsigned* __restrict__ packed32,
    const int* __restrict__ head_conn,
    const int* __restrict__ head_coeffs,
    const float* __restrict__ head_mem,
    float* __restrict__ out) {
  __shared__ unsigned addrbuf[256];
  __shared__ unsigned long long mshare[4];
  const int tid = threadIdx.x;
  const int b = blockIdx.x;
  const int w = tid >> 6, l = tid & 63;

  // one-time: 20 static B-fragments into VGPRs (160 KB table, L2-hot)
  v4i bf[2][5][2];
#pragma unroll
  for (int i = 0; i < 2; ++i)
#pragma unroll
    for (int k = 0; k < 5; ++k)
#pragma unroll
      for (int h = 0; h < 2; ++h) {
        int mf = ((2 * w + i) * 5 + k) * 2 + h;
        uint4 u = bfrag[mf * 64 + l];
        bf[i][k][h] = __builtin_bit_cast(v4i, u);
      }

  unsigned long long m0 = 0, m1 = 0, m2 = 0, m3 = 0;  // state = 0
  unsigned long long wcur = wbits[b * 128];
  unsigned NB = (unsigned)__popcll(wcur);

  const int selhi = (l & 32);
  const int sh16 = (l & 16) ? 16 : 0;

#pragma unroll 1
  for (int t = 0; t < T_; ++t) {
    int tn = (t + 1 < T_) ? t + 1 : t;
    unsigned long long wnext = wbits[b * 128 + tn];

    // ---- A-frag: lane expands its 16-bit slice of each 64-bit chunk
    unsigned long long ch0 = wcur, ch1 = m0, ch2 = m1, ch3 = m2, ch4 = m3;
    v4i A[5];
    unsigned long long chs[5] = {ch0, ch1, ch2, ch3, ch4};
#pragma unroll
    for (int c = 0; c < 5; ++c) {
      unsigned lo = (unsigned)chs[c], hi = (unsigned)(chs[c] >> 32);
      unsigned half = selhi ? hi : lo;
      unsigned b16 = (half >> sh16) & 0xFFFFu;
      v4i a;
#pragma unroll
      for (int r = 0; r < 4; ++r) {
        unsigned nib = (b16 >> (4 * r)) & 0xFu;
        a[r] = (int)((nib * 0x00204081u) & 0x01010101u);  // 4 bits -> 4 {0,1} bytes
      }
      A[c] = a;
    }

    // ---- 20 MFMAs: 2 tiles x 5 K-chunks x {lo,hi}
    v4i acc00 = (v4i){0, 0, 0, 0}, acc01 = (v4i){0, 0, 0, 0};
    v4i acc10 = (v4i){0, 0, 0, 0}, acc11 = (v4i){0, 0, 0, 0};
#pragma unroll
    for (int k = 0; k < 5; ++k) {
      acc00 = __builtin_amdgcn_mfma_i32_16x16x64_i8(A[k], bf[0][k][0], acc00, 0, 0, 0);
      acc01 = __builtin_amdgcn_mfma_i32_16x16x64_i8(A[k], bf[0][k][1], acc01, 0, 0, 0);
      acc10 = __builtin_amdgcn_mfma_i32_16x16x64_i8(A[k], bf[1][k][0], acc10, 0, 0, 0);
      acc11 = __builtin_amdgcn_mfma_i32_16x16x64_i8(A[k], bf[1][k][1], acc11, 0, 0, 0);
    }

    // ---- epilogue: addr = (Dlo + 256*Dhi + 128*257*NB) mod 2^16
    unsigned corr = (NB * 32896u) & 0xFFFFu;
    unsigned ad0 = ((unsigned)acc00[0] + ((unsigned)acc01[0] << 8) + corr) & 0xFFFFu;
    unsigned ad1 = ((unsigned)acc10[0] + ((unsigned)acc11[0] << 8) + corr) & 0xFFFFu;
    if (l < 16) {
      addrbuf[(2 * w + 0) * 16 + l] = ad0;
      addrbuf[(2 * w + 1) * 16 + l] = ad1;
    }
    __syncthreads();

    // ---- gather (dedup: waves 0-3 only, 256 requests total)
    if (w < 4) {
      int j2 = (w << 6) + l;
      unsigned ad = addrbuf[j2];
      unsigned word = packed32[((size_t)j2 << 11) + (ad >> 5)];
      unsigned long long mq = __ballot(((word >> (ad & 31)) & 1u) != 0u);
      if (l == 0) mshare[w] = mq;
    }
    __syncthreads();

    m0 = mshare[0]; m1 = mshare[1]; m2 = mshare[2]; m3 = mshare[3];
    NB = (unsigned)(__popcll(m0) + __popcll(m1) + __popcll(m2) +
                    __popcll(m3) + __popcll(wnext));
    wcur = wnext;
  }

  // ---- heads (wave 0): only the selected head per batch row
  if (w == 0) {
    int h = (int)((((wcur >> 61) & 1) << 2) | (((wcur >> 62) & 1) << 1) |
                  ((wcur >> 63) & 1));
    int ho = h * 64 + l;
    const int4* cn4 = (const int4*)(head_conn + ho * 8);
    const int4* cf4 = (const int4*)(head_coeffs + ho * 8);
    int4 cna = cn4[0], cnb = cn4[1];
    int4 cfa = cf4[0], cfb = cf4[1];
    int cns[8] = {cna.x, cna.y, cna.z, cna.w, cnb.x, cnb.y, cnb.z, cnb.w};
    int cfs[8] = {cfa.x, cfa.y, cfa.z, cfa.w, cfb.x, cfb.y, cfb.z, cfb.w};
    unsigned addr = 0;
#pragma unroll
    for (int k = 0; k < 8; ++k) {
      unsigned bit = (unsigned)((mshare[cns[k] >> 6] >> (cns[k] & 63)) & 1);
      addr += bit * (unsigned)cfs[k];
    }
    addr &= 0xFFFFu;
    out[b * 64 + l] = head_mem[((size_t)ho << 16) + addr];
  }
}

extern "C" void kernel_launch(void* const* d_in, const int* in_sizes, int n_in,
                              void* d_out, int out_size, void* d_ws, size_t ws_size,
                              hipStream_t stream) {
  const int*   bits         = (const int*)d_in[0];
  const int*   state_coeffs = (const int*)d_in[1];
  const float* state_mem    = (const float*)d_in[2];
  const int*   head_conn    = (const int*)d_in[3];
  const int*   head_coeffs  = (const int*)d_in[4];
  const float* head_mem     = (const float*)d_in[5];
  float* out = (float*)d_out;

  char* ws = (char*)d_ws;
  uint4*              bfrag  = (uint4*)ws;                        // 160 KiB
  unsigned long long* wbits  = (unsigned long long*)(ws + (160 << 10)); // 128 KiB
  unsigned*           packed = (unsigned*)(ws + (288 << 10));     // 2 MiB

  prep_bfrag<<<40, 256, 0, stream>>>(state_coeffs, bfrag);
  prep_wbits<<<4096, 256, 0, stream>>>(bits, wbits);
  prep_bitpack<<<2048, 256, 0, stream>>>(state_mem, (unsigned long long*)packed);
  scan_heads<<<128, 512, 0, stream>>>(bfrag, wbits, packed,
                                      head_conn, head_coeffs, head_mem, out);
}

// Round 4
// 348.022 us; speedup vs baseline: 1.1367x; 1.0026x over previous
//
#include <hip/hip_runtime.h>
#include <stdint.h>

#define T_ 128

typedef int v4i __attribute__((ext_vector_type(4)));

// ---------------------------------------------------------------------------
// prep 1: static B-fragments for mfma_i32_16x16x64_i8, biased i8 (byte-128).
// Fragment mf = (tau*5 + kappa)*2 + h. Lane l holds n = l&15,
// k-slots kin = (l>>4)*16 + 4r + b — identical slot->k map as scan's A, so
// any HW k-permutation cancels in the dot.
__global__ void prep_bfrag(const int* __restrict__ sc, uint4* __restrict__ bf) {
  int gid = blockIdx.x * 256 + threadIdx.x;
  if (gid >= 160 * 64) return;
  int mf = gid >> 6, l = gid & 63;
  int tau = mf / 10, rem = mf % 10;
  int kap = rem >> 1, h = rem & 1;
  int j = 16 * tau + (l & 15);
  int kinb = (l >> 4) * 16;
  unsigned wout[4];
#pragma unroll
  for (int r = 0; r < 4; ++r) {
    unsigned wrd = 0;
#pragma unroll
    for (int be = 0; be < 4; ++be) {
      int kin = kinb + 4 * r + be;
      int col = (kap == 0) ? kin : 64 + ((kap - 1) << 6) + kin;
      unsigned c = (unsigned)sc[j * 320 + col];
      unsigned byte = (h ? (c >> 8) : c) & 0xFFu;
      byte = (byte - 128u) & 0xFFu;
      wrd |= byte << (8 * be);
    }
    wout[r] = wrd;
  }
  bf[gid] = make_uint4(wout[0], wout[1], wout[2], wout[3]);
}

// prep 2: window bits packed to u64 per (b,t)
__global__ void prep_wbits(const int* __restrict__ bits,
                           unsigned long long* __restrict__ wb) {
  int gid = blockIdx.x * 256 + threadIdx.x;
  int wv = gid >> 6, lane = gid & 63;
  unsigned long long m = __ballot(bits[gid] != 0);
  if (lane == 0) wb[wv] = m;
}

// prep 3: bitpack (state_mem >= 0.5) -> 2 MiB table (L2-resident for scan)
__global__ void prep_bitpack(const float* __restrict__ sm,
                             unsigned long long* __restrict__ packed) {
  int base = blockIdx.x * (256 * 32) + threadIdx.x;
  int lane = threadIdx.x & 63;
#pragma unroll 1
  for (int it = 0; it < 32; ++it) {
    int idx = base + it * 256;
    float v = sm[idx];
    unsigned long long m = __ballot(v >= 0.5f);
    if (lane == 0) packed[idx >> 6] = m;
  }
}

// ---------------------------------------------------------------------------
// per-lane expand of a 16-bit slice into an i8 {0,1} A-fragment
static __device__ __forceinline__ v4i expand16(unsigned b16) {
  v4i a;
#pragma unroll
  for (int r = 0; r < 4; ++r) {
    unsigned nib = (b16 >> (4 * r)) & 0xFu;
    a[r] = (int)((nib * 0x00204081u) & 0x01010101u);
  }
  return a;
}

// scan + heads: 1 block per batch row, 8 waves of 64. Wave w owns N-tiles
// {2w,2w+1} = j in [32w,32w+32). Per step: 16 state-chunk MFMAs, epilogue
// selects addr in-reg, lanes<32 self-gather + ballot -> msh[t&1][w] (u32),
// window-chunk MFMAs for step t+1 fill the gather latency, ONE barrier,
// read 8 u32 state words. Heads fused on wave 0.
__global__ __launch_bounds__(512) void scan_heads(
    const uint4* __restrict__ bfrag,
    const unsigned long long* __restrict__ wbits,
    const unsigned* __restrict__ packed32,
    const int* __restrict__ head_conn,
    const int* __restrict__ head_coeffs,
    const float* __restrict__ head_mem,
    float* __restrict__ out) {
  __shared__ __align__(16) unsigned msh[2][8];
  const int tid = threadIdx.x;
  const int b = blockIdx.x;
  const int w = tid >> 6, l = tid & 63;
  const int qq = (l >> 4) & 3;          // 16-bit slice index within 64-bit chunk
  const int sh = 16 * (qq & 1);         // shift within a u32 state word
  const int wi = qq >> 1;               // u32 word parity within a u64 chunk

  // one-time: 20 static B-fragments (tiles 2w,2w+1) into registers
  v4i bf[2][5][2];
#pragma unroll
  for (int i = 0; i < 2; ++i)
#pragma unroll
    for (int k = 0; k < 5; ++k)
#pragma unroll
      for (int h = 0; h < 2; ++h) {
        int mf = ((2 * w + i) * 5 + k) * 2 + h;
        bf[i][k][h] = __builtin_bit_cast(v4i, bfrag[mf * 64 + l]);
      }

  unsigned words[8];
#pragma unroll
  for (int i = 0; i < 8; ++i) words[i] = 0u;  // state0 = 0
  unsigned long long wcur = wbits[b * 128];

  // pre-init accumulators with the t=0 window (k=0) contribution
  v4i acc[2][2];
  {
    v4i aw = expand16((unsigned)((wcur >> (16 * qq)) & 0xFFFFu));
    v4i z = (v4i){0, 0, 0, 0};
#pragma unroll
    for (int i = 0; i < 2; ++i)
#pragma unroll
      for (int h = 0; h < 2; ++h)
        acc[i][h] = __builtin_amdgcn_mfma_i32_16x16x64_i8(aw, bf[i][0][h], z, 0, 0, 0);
  }

#pragma unroll 1
  for (int t = 0; t < T_; ++t) {
    unsigned NB = (unsigned)__popcll(wcur);
#pragma unroll
    for (int i = 0; i < 8; ++i) NB += (unsigned)__popc(words[i]);

    // state-chunk A fragments and 16 MFMAs (k-chunks 1..4)
#pragma unroll
    for (int c = 0; c < 4; ++c) {
      v4i a = expand16((words[2 * c + wi] >> sh) & 0xFFFFu);
      acc[0][0] = __builtin_amdgcn_mfma_i32_16x16x64_i8(a, bf[0][c + 1][0], acc[0][0], 0, 0, 0);
      acc[0][1] = __builtin_amdgcn_mfma_i32_16x16x64_i8(a, bf[0][c + 1][1], acc[0][1], 0, 0, 0);
      acc[1][0] = __builtin_amdgcn_mfma_i32_16x16x64_i8(a, bf[1][c + 1][0], acc[1][0], 0, 0, 0);
      acc[1][1] = __builtin_amdgcn_mfma_i32_16x16x64_i8(a, bf[1][c + 1][1], acc[1][1], 0, 0, 0);
    }

    int tn = (t + 1 < T_) ? t + 1 : t;
    unsigned long long wnext = wbits[b * 128 + tn];

    // epilogue: addr for j = 32w + l (lanes 0..31), selected in-register
    unsigned corr = (NB * 32896u) & 0xFFFFu;  // 128*257 bias fixup
    unsigned lo = (unsigned)((l & 16) ? acc[1][0][0] : acc[0][0][0]);
    unsigned hi = (unsigned)((l & 16) ? acc[1][1][0] : acc[0][1][0]);
    unsigned ad = (lo + (hi << 8) + corr) & 0xFFFFu;

    // self-gather: 32 lanes/wave, 256 requests/block total
    unsigned bitv = 0;
    if (l < 32) {
      unsigned word = packed32[((size_t)(32 * w + l) << 11) + (ad >> 5)];
      bitv = (word >> (ad & 31)) & 1u;
    }
    unsigned long long mq = __ballot(bitv != 0u);
    if (l == 0) msh[t & 1][w] = (unsigned)mq;

    // fill gather latency: next step's window-chunk MFMAs into fresh accs
    {
      v4i aw = expand16((unsigned)((wnext >> (16 * qq)) & 0xFFFFu));
      v4i z = (v4i){0, 0, 0, 0};
#pragma unroll
      for (int i = 0; i < 2; ++i)
#pragma unroll
        for (int h = 0; h < 2; ++h)
          acc[i][h] = __builtin_amdgcn_mfma_i32_16x16x64_i8(aw, bf[i][0][h], z, 0, 0, 0);
    }

    __syncthreads();

    uint4 u0 = *((const uint4*)&msh[t & 1][0]);
    uint4 u1 = *((const uint4*)&msh[t & 1][4]);
    words[0] = u0.x; words[1] = u0.y; words[2] = u0.z; words[3] = u0.w;
    words[4] = u1.x; words[5] = u1.y; words[6] = u1.z; words[7] = u1.w;
    wcur = wnext;
  }

  // ---- heads (wave 0): only the selected head per batch row
  if (w == 0) {
    int h = (int)((((wcur >> 61) & 1) << 2) | (((wcur >> 62) & 1) << 1) |
                  ((wcur >> 63) & 1));
    int ho = h * 64 + l;
    const int4* cn4 = (const int4*)(head_conn + ho * 8);
    const int4* cf4 = (const int4*)(head_coeffs + ho * 8);
    int4 cna = cn4[0], cnb = cn4[1];
    int4 cfa = cf4[0], cfb = cf4[1];
    int cns[8] = {cna.x, cna.y, cna.z, cna.w, cnb.x, cnb.y, cnb.z, cnb.w};
    int cfs[8] = {cfa.x, cfa.y, cfa.z, cfa.w, cfb.x, cfb.y, cfb.z, cfb.w};
    unsigned addr = 0;
#pragma unroll
    for (int k = 0; k < 8; ++k) {
      unsigned bit = (words[cns[k] >> 5] >> (cns[k] & 31)) & 1u;
      addr += bit * (unsigned)cfs[k];
    }
    addr &= 0xFFFFu;
    out[b * 64 + l] = head_mem[((size_t)ho << 16) + addr];
  }
}

extern "C" void kernel_launch(void* const* d_in, const int* in_sizes, int n_in,
                              void* d_out, int out_size, void* d_ws, size_t ws_size,
                              hipStream_t stream) {
  const int*   bits         = (const int*)d_in[0];
  const int*   state_coeffs = (const int*)d_in[1];
  const float* state_mem    = (const float*)d_in[2];
  const int*   head_conn    = (const int*)d_in[3];
  const int*   head_coeffs  = (const int*)d_in[4];
  const float* head_mem     = (const float*)d_in[5];
  float* out = (float*)d_out;

  char* ws = (char*)d_ws;
  uint4*              bfrag  = (uint4*)ws;                             // 160 KiB
  unsigned long long* wbits  = (unsigned long long*)(ws + (160 << 10)); // 128 KiB
  unsigned*           packed = (unsigned*)(ws + (288 << 10));          // 2 MiB

  prep_bfrag<<<40, 256, 0, stream>>>(state_coeffs, bfrag);
  prep_wbits<<<4096, 256, 0, stream>>>(bits, wbits);
  prep_bitpack<<<2048, 256, 0, stream>>>(state_mem, (unsigned long long*)packed);
  scan_heads<<<128, 512, 0, stream>>>(bfrag, wbits, packed,
                                      head_conn, head_coeffs, head_mem, out);
}